// Round 3
// baseline (537.176 us; speedup 1.0000x reference)
//
#include <hip/hip_runtime.h>
#include <math.h>

#define B_ 32
#define H_ 32
#define HKV_ 8
#define G_ 4
#define D_ 128
#define BS_ 16
#define MAXNB_ 256
#define NPAGES_ 4096
#define NSLOTS_ (NPAGES_ * BS_)
#define PGSZ_ (BS_ * HKV_ * D_)   // floats per cache page-block
#define OVW_ 10                   // padded u32 words per batch in ovr bitmap
// SCALE * log2(e): work in exp2 domain (v_exp_f32 is the hw op)
#define SC_ (0.08838834764831845f * 1.4426950408889634f)
#define NEG_ -1e30f

// ---------------- kernel 1: build virtual-scatter structures (NO cache mutation) --
// map [65536]  : slot -> batch_idx+1  (rare-path lookup)
// pagemask[4096]: page -> token bitmask (build-time only)
// ovr [B][OVW_]: per-batch bitmap over page-slot positions 0..255 — bit pos set
//                iff block_tables[b][pos] points at a page containing an
//                overridden slot. Attn kernel reads 2 words once -> pure SALU
//                check per page, no memory op in the hot loop.
__global__ void build_slot_map(const int* __restrict__ slot_mapping,
                               const int* __restrict__ block_tables,
                               unsigned char* __restrict__ map,
                               unsigned int* __restrict__ pagemask,
                               unsigned int* __restrict__ ovr) {
  const int tid = threadIdx.x;   // one workgroup, 256 threads
  uint4* m4 = (uint4*)map;
#pragma unroll
  for (int i = 0; i < NSLOTS_ / 16 / 256; ++i)      // 64 KiB
    m4[tid + i * 256] = make_uint4(0u, 0u, 0u, 0u);
  uint4* p4 = (uint4*)pagemask;
#pragma unroll
  for (int i = 0; i < NPAGES_ * 4 / 16 / 256; ++i)  // 16 KiB
    p4[tid + i * 256] = make_uint4(0u, 0u, 0u, 0u);
  for (int i = tid; i < B_ * OVW_; i += 256) ovr[i] = 0u;
  __syncthreads();
  if (tid == 0) {
    // serial ascending writes -> deterministic last-wins on duplicate slots
#pragma unroll
    for (int j = 0; j < B_; ++j) {
      int s = slot_mapping[j];
      map[s] = (unsigned char)(j + 1);
      pagemask[s >> 4] |= (1u << (s & 15));
    }
  }
  __syncthreads();
  // scan all (b, pos) block-table entries against the affected-page set
  for (int e = tid; e < B_ * MAXNB_; e += 256) {
    int pgid = block_tables[e];
    if (pgid >= 0 && pgid < NPAGES_ && pagemask[pgid] != 0u) {
      int bb = e >> 8;           // MAXNB_ == 256
      int pos = e & 255;
      atomicOr(&ovr[bb * OVW_ + (pos >> 5)], 1u << (pos & 31));
    }
  }
}

// ---------------- kernel 2: flash-decode split-K attention ----------------
// Grid: B*HKV*nsplit blocks, 256 threads (4 waves).
// tok = tid>>4 in [0,16), c = tid&15 (8-float d-chunk).
// Double-buffered (unroll-2) main loop; page ids prefetched one iteration
// ahead; K reloads issued right after the dot consumes K, V reloads after the
// softmax consumes V -> >=2 pages in flight per wave, no register copies.
// __launch_bounds__(256,4): cap VGPR at 128 -> 4 blocks/CU (16 waves).
__global__ __launch_bounds__(256, 4) void attn_split(
    const float* __restrict__ q,
    const float* __restrict__ k_new,        // [B][HKV][D] new-token k
    const float* __restrict__ v_new,        // [B][HKV][D] new-token v
    const float* __restrict__ k_cache,
    const float* __restrict__ v_cache,
    const int* __restrict__ block_tables,
    const int* __restrict__ context_lens,
    const unsigned char* __restrict__ map,
    const unsigned int* __restrict__ ovr,
    float* __restrict__ O_part,   // [B][HKV][G][nsplit][D]
    float* __restrict__ M_part,   // [B][HKV][G][nsplit]
    float* __restrict__ L_part,   // [B][HKV][G][nsplit]
    int nsplit)
{
  __shared__ float Ml[4][4];        // [wave][g]
  __shared__ float Ll[4][4];
  __shared__ float Ob[4][4][128];   // [wave][g][d]  (8 KB)

  const int tid = threadIdx.x;
  const int tok = tid >> 4;
  const int c = tid & 15;

  const int s  = blockIdx.x % nsplit;
  const int bk = blockIdx.x / nsplit;
  const int kv = bk % HKV_;
  const int b  = bk / HKV_;

  // q fragment for 4 group heads, pre-scaled into exp2 domain
  float qr[G_][8];
#pragma unroll
  for (int g = 0; g < G_; ++g) {
    const float* qp = q + ((size_t)(b * H_ + kv * G_ + g)) * D_ + c * 8;
    float4 a0 = *(const float4*)qp;
    float4 a1 = *(const float4*)(qp + 4);
    qr[g][0] = a0.x * SC_; qr[g][1] = a0.y * SC_;
    qr[g][2] = a0.z * SC_; qr[g][3] = a0.w * SC_;
    qr[g][4] = a1.x * SC_; qr[g][5] = a1.y * SC_;
    qr[g][6] = a1.z * SC_; qr[g][7] = a1.w * SC_;
  }

  float m2[G_], l[G_], o[G_][8];
#pragma unroll
  for (int g = 0; g < G_; ++g) {
    m2[g] = NEG_; l[g] = 0.f;
#pragma unroll
    for (int j = 0; j < 8; ++j) o[g][j] = 0.f;
  }

  const int ctx = context_lens[b];
  const int pages_total = (ctx + BS_ - 1) / BS_;
  const int p_per = (pages_total + nsplit - 1) / nsplit;   // even split
  const int p0 = s * p_per;
  const int p1 = min(p0 + p_per, pages_total);

  // per-thread element offset inside one cache block (floats): 32 B contiguous
  const int toff = tok * (HKV_ * D_) + kv * D_ + c * 8;
  const int bt_base = b * MAXNB_;

  // override-bit window for this split: bits [p0, p0+p_per) of ovr[b]
  unsigned long long dwr;
  if (p_per <= 32) {
    const unsigned int* ow = ovr + b * OVW_;
    const int i0 = p0 >> 5, s0 = p0 & 31;
    unsigned long long lo = ow[i0], hi = ow[i0 + 1];
    dwr = ((hi << 32) | lo) >> s0;
  } else {
    dwr = ~0ull;   // fallback: always consult map (correct, slower; unused path)
  }

  struct PBuf { float4 k0, k1, v0, v1; int blk; };
  PBuf A, B;

  auto fill = [&](PBuf& P, int id, bool ok) {
    P.blk = id;
    const int nb = id < 0 ? 0 : id;
    const float* kp = k_cache + (size_t)nb * PGSZ_ + toff;
    const float* vp = v_cache + (size_t)nb * PGSZ_ + toff;
    if (ok) {
      P.k0 = *(const float4*)kp; P.k1 = *(const float4*)(kp + 4);
      P.v0 = *(const float4*)vp; P.v1 = *(const float4*)(vp + 4);
    } else {
      P.k0 = P.k1 = P.v0 = P.v1 = make_float4(0.f, 0.f, 0.f, 0.f);
    }
  };

  // one page step: override-check, dot (K dies -> reload K), shfl-reduce,
  // online softmax (V dies -> reload V), advance buffer to page id 'nid'.
  auto step = [&](PBuf& P, int pgx, int nid, bool filln, bool chk) {
    const int thisblk = P.blk;
    if (chk) {                       // wave-uniform, rare
      const int bc0 = thisblk < 0 ? 0 : thisblk;
      const int mj = map[bc0 * BS_ + tok];
      if (mj != 0) {
        const int j = mj - 1;
        const float* kp = k_new + ((size_t)(j * HKV_ + kv)) * D_ + c * 8;
        const float* vp = v_new + ((size_t)(j * HKV_ + kv)) * D_ + c * 8;
        P.k0 = *(const float4*)kp; P.k1 = *(const float4*)(kp + 4);
        P.v0 = *(const float4*)vp; P.v1 = *(const float4*)(vp + 4);
      }
    }
    float dt[G_];
#pragma unroll
    for (int g = 0; g < G_; ++g) {
      dt[g] = qr[g][0] * P.k0.x + qr[g][1] * P.k0.y + qr[g][2] * P.k0.z + qr[g][3] * P.k0.w
            + qr[g][4] * P.k1.x + qr[g][5] * P.k1.y + qr[g][6] * P.k1.z + qr[g][7] * P.k1.w;
    }
    // K consumed: issue next page's K loads now (in flight under shfl+softmax)
    const int nb = nid < 0 ? 0 : nid;
    const float* nkp = k_cache + (size_t)nb * PGSZ_ + toff;
    const float* nvp = v_cache + (size_t)nb * PGSZ_ + toff;
    if (filln) { P.k0 = *(const float4*)nkp; P.k1 = *(const float4*)(nkp + 4); }
    // reduce partial dots across the 16 c-lanes (lanes 0-15 share a token)
#pragma unroll
    for (int off = 1; off < 16; off <<= 1) {
#pragma unroll
      for (int g = 0; g < G_; ++g) dt[g] += __shfl_xor(dt[g], off, 16);
    }
    const int pos = pgx * BS_ + tok;
    if ((pos < ctx) && (thisblk >= 0)) {
#pragma unroll
      for (int g = 0; g < G_; ++g) {
        float t2 = dt[g];
        float mn = fmaxf(m2[g], t2);
        float al = exp2f(m2[g] - mn);
        float p  = exp2f(t2 - mn);
        l[g] = l[g] * al + p;
        m2[g] = mn;
        o[g][0] = o[g][0] * al + p * P.v0.x;
        o[g][1] = o[g][1] * al + p * P.v0.y;
        o[g][2] = o[g][2] * al + p * P.v0.z;
        o[g][3] = o[g][3] * al + p * P.v0.w;
        o[g][4] = o[g][4] * al + p * P.v1.x;
        o[g][5] = o[g][5] * al + p * P.v1.y;
        o[g][6] = o[g][6] * al + p * P.v1.z;
        o[g][7] = o[g][7] * al + p * P.v1.w;
      }
    }
    // V consumed: issue next page's V loads
    if (filln) { P.v0 = *(const float4*)nvp; P.v1 = *(const float4*)(nvp + 4); }
    P.blk = nid;
  };

  // prologue: pages p0 (A) and p0+1 (B) in flight; ids for p0+2/p0+3 prefetched
  {
    int i0 = (p0 < p1) ? block_tables[bt_base + p0] : 0;
    int i1 = (p0 + 1 < p1) ? block_tables[bt_base + p0 + 1] : 0;
    fill(A, i0, p0 < p1);
    fill(B, i1, p0 + 1 < p1);
  }
  int nidA = (p0 + 2 < p1) ? block_tables[bt_base + p0 + 2] : 0;
  int nidB = (p0 + 3 < p1) ? block_tables[bt_base + p0 + 3] : 0;

  int pg = p0;
  for (; pg + 1 < p1; pg += 2) {
    step(A, pg,     nidA, pg + 2 < p1, (dwr & 1ull) != 0);
    step(B, pg + 1, nidB, pg + 3 < p1, (dwr & 2ull) != 0);
    nidA = (pg + 4 < p1) ? block_tables[bt_base + pg + 4] : 0;
    nidB = (pg + 5 < p1) ? block_tables[bt_base + pg + 5] : 0;
    dwr >>= 2;
  }
  if (pg < p1) step(A, pg, 0, false, (dwr & 1ull) != 0);

  // ---- intra-wave merge of 4 token-partials (lanes ^16, ^32) ----
#pragma unroll
  for (int off = 16; off < 64; off <<= 1) {
#pragma unroll
    for (int g = 0; g < G_; ++g) {
      float mo = __shfl_xor(m2[g], off, 64);
      float lo = __shfl_xor(l[g], off, 64);
      float mn = fmaxf(m2[g], mo);
      float f1 = exp2f(m2[g] - mn);
      float f2 = exp2f(mo - mn);
      l[g] = f1 * l[g] + f2 * lo;
      m2[g] = mn;
#pragma unroll
      for (int j = 0; j < 8; ++j)
        o[g][j] = f1 * o[g][j] + f2 * __shfl_xor(o[g][j], off, 64);
    }
  }

  // ---- cross-wave merge through 8 KB LDS ----
  const int w = tid >> 6;
  if ((tid & 63) == 0) {
#pragma unroll
    for (int g = 0; g < G_; ++g) { Ml[w][g] = m2[g]; Ll[w][g] = l[g]; }
  }
  if (((tid >> 4) & 3) == 0) {   // one token-lane-group per wave writes
#pragma unroll
    for (int g = 0; g < G_; ++g) {
      float* dst = &Ob[w][g][c * 8];
      *(float4*)dst       = make_float4(o[g][0], o[g][1], o[g][2], o[g][3]);
      *(float4*)(dst + 4) = make_float4(o[g][4], o[g][5], o[g][6], o[g][7]);
    }
  }
  __syncthreads();

  const int g2 = tid >> 6;          // head within group
  const int dd = (tid & 63) * 2;    // 2 d-elements per thread
  float M = NEG_;
#pragma unroll
  for (int wv = 0; wv < 4; ++wv) M = fmaxf(M, Ml[wv][g2]);
  float Ls = 0.f, a0 = 0.f, a1 = 0.f;
#pragma unroll
  for (int wv = 0; wv < 4; ++wv) {
    float f = exp2f(Ml[wv][g2] - M);
    Ls += f * Ll[wv][g2];
    float2 ov = *(const float2*)&Ob[wv][g2][dd];
    a0 += f * ov.x;
    a1 += f * ov.y;
  }
  const size_t pi = ((size_t)((b * HKV_ + kv) * G_ + g2) * nsplit + s);
  O_part[pi * D_ + dd]     = a0;
  O_part[pi * D_ + dd + 1] = a1;
  if (dd == 0) { M_part[pi] = M; L_part[pi] = Ls; }
}

// ---------------- kernel 3: combine splits ----------------
__global__ void combine_splits(const float* __restrict__ O_part,
                               const float* __restrict__ M_part,
                               const float* __restrict__ L_part,
                               const int* __restrict__ context_lens,
                               float* __restrict__ out, int nsplit) {
  const int blk = blockIdx.x;      // b*H + h  (h = kv*4+g)
  const int b = blk >> 5;
  const int d = threadIdx.x;       // 128 threads
  const int ctx = context_lens[b];
  float r = 0.f;
  if (ctx > 0) {
    const size_t base = (size_t)blk * nsplit;
    float M = NEG_;
    for (int s = 0; s < nsplit; ++s) M = fmaxf(M, M_part[base + s]);
    float den = 0.f, acc = 0.f;
    for (int s = 0; s < nsplit; ++s) {
      float f = exp2f(M_part[base + s] - M);
      den += f * L_part[base + s];
      acc += f * O_part[(base + s) * D_ + d];
    }
    r = den > 0.f ? acc / den : 0.f;
  }
  out[(size_t)blk * D_ + d] = r;
}

extern "C" void kernel_launch(void* const* d_in, const int* in_sizes, int n_in,
                              void* d_out, int out_size, void* d_ws, size_t ws_size,
                              hipStream_t stream) {
  const float* q = (const float*)d_in[0];
  const float* k = (const float*)d_in[1];
  const float* v = (const float*)d_in[2];
  const float* k_cache = (const float*)d_in[3];   // read-only: no restore cost
  const float* v_cache = (const float*)d_in[4];
  const int* slot_mapping = (const int*)d_in[5];
  const int* block_tables = (const int*)d_in[6];
  const int* context_lens = (const int*)d_in[7];
  float* out = (float*)d_out;

  // ws layout: [64K map][16K pagemask][2K ovr][O_part][M_part][L_part]
  const size_t map_bytes = NSLOTS_;
  const size_t pmask_bytes = NPAGES_ * sizeof(unsigned int);
  const size_t ovr_bytes = 2048;     // 32*OVW_*4 = 1280, padded
  unsigned char* map = (unsigned char*)d_ws;
  unsigned int* pagemask = (unsigned int*)((char*)d_ws + map_bytes);
  unsigned int* ovr = (unsigned int*)((char*)d_ws + map_bytes + pmask_bytes);

  int nsplit = 16;
  while (nsplit > 1) {
    size_t need = map_bytes + pmask_bytes + ovr_bytes +
                  (size_t)B_ * HKV_ * G_ * nsplit * (D_ + 2) * sizeof(float);
    if (need <= ws_size) break;
    nsplit >>= 1;
  }
  float* O_part = (float*)((char*)d_ws + map_bytes + pmask_bytes + ovr_bytes);
  float* M_part = O_part + (size_t)B_ * HKV_ * G_ * nsplit * D_;
  float* L_part = M_part + (size_t)B_ * HKV_ * G_ * nsplit;

  build_slot_map<<<1, 256, 0, stream>>>(slot_mapping, block_tables,
                                        map, pagemask, ovr);
  attn_split<<<B_ * HKV_ * nsplit, 256, 0, stream>>>(
      q, k, v, k_cache, v_cache, block_tables, context_lens, map, ovr,
      O_part, M_part, L_part, nsplit);
  combine_splits<<<B_ * H_, D_, 0, stream>>>(O_part, M_part, L_part,
                                             context_lens, out, nsplit);
}

// Round 4
// 535.348 us; speedup vs baseline: 1.0034x; 1.0034x over previous
//
#include <hip/hip_runtime.h>
#include <math.h>

#define B_ 32
#define H_ 32
#define HKV_ 8
#define G_ 4
#define D_ 128
#define BS_ 16
#define MAXNB_ 256
#define NPAGES_ 4096
#define NSLOTS_ (NPAGES_ * BS_)
#define PGSZ_ (BS_ * HKV_ * D_)   // floats per cache page-block
#define NSPLIT_ 8                 // p_per <= 32 always (MAXNB_/NSPLIT_)
#define OVW_ 10                   // padded u32 words per batch in ovr bitmap
// SCALE * log2(e): work in exp2 domain (v_exp_f32 is the hw op)
#define SC_ (0.08838834764831845f * 1.4426950408889634f)
#define NEG_ -1e30f

// ---------------- kernel 1: build virtual-scatter structures (NO cache mutation) --
// map [65536]   : slot -> batch_idx+1  (rare-path lookup)
// pagemask[4096]: page -> token bitmask (build-time only)
// ovr [B][OVW_] : per-batch bitmap over block-table positions 0..255 — bit pos
//                 set iff block_tables[b][pos] names a page holding an
//                 overridden slot. Scalar-register check per page in attn.
__global__ void build_slot_map(const int* __restrict__ slot_mapping,
                               const int* __restrict__ block_tables,
                               unsigned char* __restrict__ map,
                               unsigned int* __restrict__ pagemask,
                               unsigned int* __restrict__ ovr) {
  const int tid = threadIdx.x;   // one workgroup, 256 threads
  uint4* m4 = (uint4*)map;
#pragma unroll
  for (int i = 0; i < NSLOTS_ / 16 / 256; ++i)      // 64 KiB
    m4[tid + i * 256] = make_uint4(0u, 0u, 0u, 0u);
  uint4* p4 = (uint4*)pagemask;
#pragma unroll
  for (int i = 0; i < NPAGES_ * 4 / 16 / 256; ++i)  // 16 KiB
    p4[tid + i * 256] = make_uint4(0u, 0u, 0u, 0u);
  for (int i = tid; i < B_ * OVW_; i += 256) ovr[i] = 0u;
  __syncthreads();
  if (tid == 0) {
    // serial ascending writes -> deterministic last-wins on duplicate slots
#pragma unroll
    for (int j = 0; j < B_; ++j) {
      int s = slot_mapping[j];
      map[s] = (unsigned char)(j + 1);
      pagemask[s >> 4] |= (1u << (s & 15));
    }
  }
  __syncthreads();
  // scan all (b, pos) block-table entries against the affected-page set
  for (int e = tid; e < B_ * MAXNB_; e += 256) {
    int pgid = block_tables[e];
    if (pgid >= 0 && pgid < NPAGES_ && pagemask[pgid] != 0u) {
      int bb = e >> 8;           // MAXNB_ == 256
      int pos = e & 255;
      atomicOr(&ovr[bb * OVW_ + (pos >> 5)], 1u << (pos & 31));
    }
  }
}

// ---------------- kernel 2: flash-decode split-K attention ----------------
// Grid: B*HKV*NSPLIT_ blocks, 256 threads (4 waves).
// tok = tid>>4 in [0,16), c = tid&15 (8-float d-chunk).
// Explicit flat double-buffer (named regs, no struct/lambda): K loads for
// page+2 issue right after the dot consumes K; V loads right after softmax
// consumes V. launch_bounds(256,4) caps VGPR at 128 -> 4 blocks/CU.
__global__ __launch_bounds__(256, 4) void attn_split(
    const float* __restrict__ q,
    const float* __restrict__ k_new,        // [B][HKV][D] new-token k
    const float* __restrict__ v_new,        // [B][HKV][D] new-token v
    const float* __restrict__ k_cache,
    const float* __restrict__ v_cache,
    const int* __restrict__ block_tables,
    const int* __restrict__ context_lens,
    const unsigned char* __restrict__ map,
    const unsigned int* __restrict__ ovr,
    float* __restrict__ O_part,   // [B][HKV][G][NSPLIT_][D]
    float* __restrict__ M_part,   // [B][HKV][G][NSPLIT_]
    float* __restrict__ L_part)   // [B][HKV][G][NSPLIT_]
{
  __shared__ float Ml[4][4];        // [wave][g]
  __shared__ float Ll[4][4];
  __shared__ float Ob[4][4][128];   // [wave][g][d]  (8 KB)

  const int tid = threadIdx.x;
  const int tok = tid >> 4;
  const int c = tid & 15;

  const int s  = blockIdx.x % NSPLIT_;
  const int bk = blockIdx.x / NSPLIT_;
  const int kv = bk % HKV_;
  const int b  = bk / HKV_;

  // q fragment for 4 group heads, pre-scaled into exp2 domain
  float qr[G_][8];
#pragma unroll
  for (int g = 0; g < G_; ++g) {
    const float* qp = q + ((size_t)(b * H_ + kv * G_ + g)) * D_ + c * 8;
    float4 a0 = *(const float4*)qp;
    float4 a1 = *(const float4*)(qp + 4);
    qr[g][0] = a0.x * SC_; qr[g][1] = a0.y * SC_;
    qr[g][2] = a0.z * SC_; qr[g][3] = a0.w * SC_;
    qr[g][4] = a1.x * SC_; qr[g][5] = a1.y * SC_;
    qr[g][6] = a1.z * SC_; qr[g][7] = a1.w * SC_;
  }

  float m2[G_], l[G_], o[G_][8];
#pragma unroll
  for (int g = 0; g < G_; ++g) {
    m2[g] = NEG_; l[g] = 0.f;
#pragma unroll
    for (int j = 0; j < 8; ++j) o[g][j] = 0.f;
  }

  const int ctx = context_lens[b];
  const int pages_total = (ctx + BS_ - 1) / BS_;
  const int p_per = (pages_total + NSPLIT_ - 1) / NSPLIT_;   // <= 32
  const int p0 = s * p_per;
  const int p1 = min(p0 + p_per, pages_total);

  // per-thread element offset inside one cache block (floats): 32 B contiguous
  const int toff = tok * (HKV_ * D_) + kv * D_ + c * 8;
  const int bt_base = b * MAXNB_;

  // override-bit window: bits [p0, p0+32) of ovr[b]  (p_per <= 32 guaranteed)
  unsigned long long dwr;
  {
    const unsigned int* ow = ovr + b * OVW_;
    const int i0 = p0 >> 5, s0 = p0 & 31;
    unsigned long long lo = ow[i0], hi = ow[i0 + 1];
    dwr = ((hi << 32) | lo) >> s0;
  }

  // double-buffer registers (flat names -> allocator-friendly)
  float4 ak0, ak1, av0, av1, bk0, bk1, bv0, bv1;
  int ablk = 0, bblk = 0;

  // prologue: fill A (p0) and B (p0+1)
  if (p0 < p1) {
    ablk = block_tables[bt_base + p0];
    const int nb = ablk < 0 ? 0 : ablk;
    const float* kp = k_cache + (size_t)nb * PGSZ_ + toff;
    const float* vp = v_cache + (size_t)nb * PGSZ_ + toff;
    ak0 = *(const float4*)kp; ak1 = *(const float4*)(kp + 4);
    av0 = *(const float4*)vp; av1 = *(const float4*)(vp + 4);
  }
  if (p0 + 1 < p1) {
    bblk = block_tables[bt_base + p0 + 1];
    const int nb = bblk < 0 ? 0 : bblk;
    const float* kp = k_cache + (size_t)nb * PGSZ_ + toff;
    const float* vp = v_cache + (size_t)nb * PGSZ_ + toff;
    bk0 = *(const float4*)kp; bk1 = *(const float4*)(kp + 4);
    bv0 = *(const float4*)vp; bv1 = *(const float4*)(vp + 4);
  }
  int nidA = (p0 + 2 < p1) ? block_tables[bt_base + p0 + 2] : 0;
  int nidB = (p0 + 3 < p1) ? block_tables[bt_base + p0 + 3] : 0;

  int pg = p0;
  for (; pg + 1 < p1; pg += 2) {
    // ================= page pg (buffer A) =================
    if (dwr & 1ull) {                       // wave-uniform, rare
      const int bc0 = ablk < 0 ? 0 : ablk;
      const int mj = map[bc0 * BS_ + tok];
      if (mj != 0) {
        const int j = mj - 1;
        const float* kp = k_new + ((size_t)(j * HKV_ + kv)) * D_ + c * 8;
        const float* vp = v_new + ((size_t)(j * HKV_ + kv)) * D_ + c * 8;
        ak0 = *(const float4*)kp; ak1 = *(const float4*)(kp + 4);
        av0 = *(const float4*)vp; av1 = *(const float4*)(vp + 4);
      }
    }
    float dtA[G_];
#pragma unroll
    for (int g = 0; g < G_; ++g) {
      dtA[g] = qr[g][0] * ak0.x + qr[g][1] * ak0.y + qr[g][2] * ak0.z + qr[g][3] * ak0.w
             + qr[g][4] * ak1.x + qr[g][5] * ak1.y + qr[g][6] * ak1.z + qr[g][7] * ak1.w;
    }
    // K(A) consumed -> issue K loads for page pg+2 into A
    {
      const int nb = nidA < 0 ? 0 : nidA;
      const float* kp = k_cache + (size_t)nb * PGSZ_ + toff;
      if (pg + 2 < p1) { ak0 = *(const float4*)kp; ak1 = *(const float4*)(kp + 4); }
    }
#pragma unroll
    for (int off = 1; off < 16; off <<= 1) {
#pragma unroll
      for (int g = 0; g < G_; ++g) dtA[g] += __shfl_xor(dtA[g], off, 16);
    }
    {
      const int pos = pg * BS_ + tok;
      if ((pos < ctx) && (ablk >= 0)) {
#pragma unroll
        for (int g = 0; g < G_; ++g) {
          float t2 = dtA[g];
          float mn = fmaxf(m2[g], t2);
          float al = exp2f(m2[g] - mn);
          float p  = exp2f(t2 - mn);
          l[g] = l[g] * al + p;
          m2[g] = mn;
          o[g][0] = o[g][0] * al + p * av0.x;
          o[g][1] = o[g][1] * al + p * av0.y;
          o[g][2] = o[g][2] * al + p * av0.z;
          o[g][3] = o[g][3] * al + p * av0.w;
          o[g][4] = o[g][4] * al + p * av1.x;
          o[g][5] = o[g][5] * al + p * av1.y;
          o[g][6] = o[g][6] * al + p * av1.z;
          o[g][7] = o[g][7] * al + p * av1.w;
        }
      }
    }
    // V(A) consumed -> issue V loads for page pg+2 into A
    {
      const int nb = nidA < 0 ? 0 : nidA;
      const float* vp = v_cache + (size_t)nb * PGSZ_ + toff;
      if (pg + 2 < p1) { av0 = *(const float4*)vp; av1 = *(const float4*)(vp + 4); }
      ablk = nidA;
    }

    // ================= page pg+1 (buffer B) =================
    if (dwr & 2ull) {
      const int bc0 = bblk < 0 ? 0 : bblk;
      const int mj = map[bc0 * BS_ + tok];
      if (mj != 0) {
        const int j = mj - 1;
        const float* kp = k_new + ((size_t)(j * HKV_ + kv)) * D_ + c * 8;
        const float* vp = v_new + ((size_t)(j * HKV_ + kv)) * D_ + c * 8;
        bk0 = *(const float4*)kp; bk1 = *(const float4*)(kp + 4);
        bv0 = *(const float4*)vp; bv1 = *(const float4*)(vp + 4);
      }
    }
    float dtB[G_];
#pragma unroll
    for (int g = 0; g < G_; ++g) {
      dtB[g] = qr[g][0] * bk0.x + qr[g][1] * bk0.y + qr[g][2] * bk0.z + qr[g][3] * bk0.w
             + qr[g][4] * bk1.x + qr[g][5] * bk1.y + qr[g][6] * bk1.z + qr[g][7] * bk1.w;
    }
    // K(B) consumed -> issue K loads for page pg+3 into B
    {
      const int nb = nidB < 0 ? 0 : nidB;
      const float* kp = k_cache + (size_t)nb * PGSZ_ + toff;
      if (pg + 3 < p1) { bk0 = *(const float4*)kp; bk1 = *(const float4*)(kp + 4); }
    }
#pragma unroll
    for (int off = 1; off < 16; off <<= 1) {
#pragma unroll
      for (int g = 0; g < G_; ++g) dtB[g] += __shfl_xor(dtB[g], off, 16);
    }
    {
      const int pos = (pg + 1) * BS_ + tok;
      if ((pos < ctx) && (bblk >= 0)) {
#pragma unroll
        for (int g = 0; g < G_; ++g) {
          float t2 = dtB[g];
          float mn = fmaxf(m2[g], t2);
          float al = exp2f(m2[g] - mn);
          float p  = exp2f(t2 - mn);
          l[g] = l[g] * al + p;
          m2[g] = mn;
          o[g][0] = o[g][0] * al + p * bv0.x;
          o[g][1] = o[g][1] * al + p * bv0.y;
          o[g][2] = o[g][2] * al + p * bv0.z;
          o[g][3] = o[g][3] * al + p * bv0.w;
          o[g][4] = o[g][4] * al + p * bv1.x;
          o[g][5] = o[g][5] * al + p * bv1.y;
          o[g][6] = o[g][6] * al + p * bv1.z;
          o[g][7] = o[g][7] * al + p * bv1.w;
        }
      }
    }
    // V(B) consumed -> issue V loads for page pg+3 into B
    {
      const int nb = nidB < 0 ? 0 : nidB;
      const float* vp = v_cache + (size_t)nb * PGSZ_ + toff;
      if (pg + 3 < p1) { bv0 = *(const float4*)vp; bv1 = *(const float4*)(vp + 4); }
      bblk = nidB;
    }

    nidA = (pg + 4 < p1) ? block_tables[bt_base + pg + 4] : 0;
    nidB = (pg + 5 < p1) ? block_tables[bt_base + pg + 5] : 0;
    dwr >>= 2;
  }

  // tail page (buffer A)
  if (pg < p1) {
    if (dwr & 1ull) {
      const int bc0 = ablk < 0 ? 0 : ablk;
      const int mj = map[bc0 * BS_ + tok];
      if (mj != 0) {
        const int j = mj - 1;
        const float* kp = k_new + ((size_t)(j * HKV_ + kv)) * D_ + c * 8;
        const float* vp = v_new + ((size_t)(j * HKV_ + kv)) * D_ + c * 8;
        ak0 = *(const float4*)kp; ak1 = *(const float4*)(kp + 4);
        av0 = *(const float4*)vp; av1 = *(const float4*)(vp + 4);
      }
    }
    float dtA[G_];
#pragma unroll
    for (int g = 0; g < G_; ++g) {
      dtA[g] = qr[g][0] * ak0.x + qr[g][1] * ak0.y + qr[g][2] * ak0.z + qr[g][3] * ak0.w
             + qr[g][4] * ak1.x + qr[g][5] * ak1.y + qr[g][6] * ak1.z + qr[g][7] * ak1.w;
    }
#pragma unroll
    for (int off = 1; off < 16; off <<= 1) {
#pragma unroll
      for (int g = 0; g < G_; ++g) dtA[g] += __shfl_xor(dtA[g], off, 16);
    }
    const int pos = pg * BS_ + tok;
    if ((pos < ctx) && (ablk >= 0)) {
#pragma unroll
      for (int g = 0; g < G_; ++g) {
        float t2 = dtA[g];
        float mn = fmaxf(m2[g], t2);
        float al = exp2f(m2[g] - mn);
        float p  = exp2f(t2 - mn);
        l[g] = l[g] * al + p;
        m2[g] = mn;
        o[g][0] = o[g][0] * al + p * av0.x;
        o[g][1] = o[g][1] * al + p * av0.y;
        o[g][2] = o[g][2] * al + p * av0.z;
        o[g][3] = o[g][3] * al + p * av0.w;
        o[g][4] = o[g][4] * al + p * av1.x;
        o[g][5] = o[g][5] * al + p * av1.y;
        o[g][6] = o[g][6] * al + p * av1.z;
        o[g][7] = o[g][7] * al + p * av1.w;
      }
    }
  }

  // ---- intra-wave merge of 4 token-partials (lanes ^16, ^32) ----
#pragma unroll
  for (int off = 16; off < 64; off <<= 1) {
#pragma unroll
    for (int g = 0; g < G_; ++g) {
      float mo = __shfl_xor(m2[g], off, 64);
      float lo = __shfl_xor(l[g], off, 64);
      float mn = fmaxf(m2[g], mo);
      float f1 = exp2f(m2[g] - mn);
      float f2 = exp2f(mo - mn);
      l[g] = f1 * l[g] + f2 * lo;
      m2[g] = mn;
#pragma unroll
      for (int j = 0; j < 8; ++j)
        o[g][j] = f1 * o[g][j] + f2 * __shfl_xor(o[g][j], off, 64);
    }
  }

  // ---- cross-wave merge through 8 KB LDS ----
  const int w = tid >> 6;
  if ((tid & 63) == 0) {
#pragma unroll
    for (int g = 0; g < G_; ++g) { Ml[w][g] = m2[g]; Ll[w][g] = l[g]; }
  }
  if (((tid >> 4) & 3) == 0) {   // one token-lane-group per wave writes
#pragma unroll
    for (int g = 0; g < G_; ++g) {
      float* dst = &Ob[w][g][c * 8];
      *(float4*)dst       = make_float4(o[g][0], o[g][1], o[g][2], o[g][3]);
      *(float4*)(dst + 4) = make_float4(o[g][4], o[g][5], o[g][6], o[g][7]);
    }
  }
  __syncthreads();

  const int g2 = tid >> 6;          // head within group
  const int dd = (tid & 63) * 2;    // 2 d-elements per thread
  float M = NEG_;
#pragma unroll
  for (int wv = 0; wv < 4; ++wv) M = fmaxf(M, Ml[wv][g2]);
  float Ls = 0.f, a0 = 0.f, a1 = 0.f;
#pragma unroll
  for (int wv = 0; wv < 4; ++wv) {
    float f = exp2f(Ml[wv][g2] - M);
    Ls += f * Ll[wv][g2];
    float2 ov = *(const float2*)&Ob[wv][g2][dd];
    a0 += f * ov.x;
    a1 += f * ov.y;
  }
  const size_t pi = ((size_t)((b * HKV_ + kv) * G_ + g2) * NSPLIT_ + s);
  O_part[pi * D_ + dd]     = a0;
  O_part[pi * D_ + dd + 1] = a1;
  if (dd == 0) { M_part[pi] = M; L_part[pi] = Ls; }
}

// ---------------- kernel 3: combine splits ----------------
__global__ void combine_splits(const float* __restrict__ O_part,
                               const float* __restrict__ M_part,
                               const float* __restrict__ L_part,
                               const int* __restrict__ context_lens,
                               float* __restrict__ out) {
  const int blk = blockIdx.x;      // b*H + h  (h = kv*4+g)
  const int b = blk >> 5;
  const int d = threadIdx.x;       // 128 threads
  const int ctx = context_lens[b];
  float r = 0.f;
  if (ctx > 0) {
    const size_t base = (size_t)blk * NSPLIT_;
    float M = NEG_;
#pragma unroll
    for (int s = 0; s < NSPLIT_; ++s) M = fmaxf(M, M_part[base + s]);
    float den = 0.f, acc = 0.f;
#pragma unroll
    for (int s = 0; s < NSPLIT_; ++s) {
      float f = exp2f(M_part[base + s] - M);
      den += f * L_part[base + s];
      acc += f * O_part[(base + s) * D_ + d];
    }
    r = den > 0.f ? acc / den : 0.f;
  }
  out[(size_t)blk * D_ + d] = r;
}

extern "C" void kernel_launch(void* const* d_in, const int* in_sizes, int n_in,
                              void* d_out, int out_size, void* d_ws, size_t ws_size,
                              hipStream_t stream) {
  const float* q = (const float*)d_in[0];
  const float* k = (const float*)d_in[1];
  const float* v = (const float*)d_in[2];
  const float* k_cache = (const float*)d_in[3];   // read-only: no restore cost
  const float* v_cache = (const float*)d_in[4];
  const int* slot_mapping = (const int*)d_in[5];
  const int* block_tables = (const int*)d_in[6];
  const int* context_lens = (const int*)d_in[7];
  float* out = (float*)d_out;

  // ws layout: [64K map][16K pagemask][2K ovr][O_part][M_part][L_part]
  const size_t map_bytes = NSLOTS_;
  const size_t pmask_bytes = NPAGES_ * sizeof(unsigned int);
  const size_t ovr_bytes = 2048;     // 32*OVW_*4 = 1280, padded
  unsigned char* map = (unsigned char*)d_ws;
  unsigned int* pagemask = (unsigned int*)((char*)d_ws + map_bytes);
  unsigned int* ovr = (unsigned int*)((char*)d_ws + map_bytes + pmask_bytes);

  float* O_part = (float*)((char*)d_ws + map_bytes + pmask_bytes + ovr_bytes);
  float* M_part = O_part + (size_t)B_ * HKV_ * G_ * NSPLIT_ * D_;
  float* L_part = M_part + (size_t)B_ * HKV_ * G_ * NSPLIT_;

  build_slot_map<<<1, 256, 0, stream>>>(slot_mapping, block_tables,
                                        map, pagemask, ovr);
  attn_split<<<B_ * HKV_ * NSPLIT_, 256, 0, stream>>>(
      q, k, v, k_cache, v_cache, block_tables, context_lens, map, ovr,
      O_part, M_part, L_part);
  combine_splits<<<B_ * H_, D_, 0, stream>>>(O_part, M_part, L_part,
                                             context_lens, out);
}